// Round 3
// baseline (270.998 us; speedup 1.0000x reference)
//
#include <hip/hip_runtime.h>
#include <cmath>

// R7: bulletproof per-wave pipeline. R4/R5/R6 all pinned at ~100us with
// VALUBusy 27% (= exactly the VALU issue work / dur), nothing saturated ->
// per-wave phase-boundary stalls. All three rounds shared: single LDS
// buffer, prefetch distance 1, stage->FMA same-buffer write->read on the
// critical path each chunk. R7 removes every wait by DISTANCE:
//  - double-buffered wave-private LDS (2 x 4 KB): FMA(k) reads buf[k&1]
//    written one full chunk ago -> lgkm satisfied on arrival.
//  - two register load-buffers LA/LB, prefetch distance 2 chunks
//    (~2600 cyc >> 900 cyc HBM latency) -> vmcnt satisfied on arrival.
//  - no sched_barriers: phases are hazard-free, scheduler may interleave
//    exp VALU with ds_read latency freely.
// Keep: barrier-free main loop (same-wave DS pipe is in-order),
// XOR-swizzle addr(c,rg)=32c+4*(((c>>2)^rg)&7) (reads 2 addr/4-bank
// group = free; b128 wave64 8-phase floor), contiguous [block][800]
// partials, fused sinkhorn+finalize, no min-waves launch_bounds clause.

#define TPB 256
#define CCH 32                        // columns per chunk per wave
#define NCH 8                         // chunks per wave stripe
#define STRIPE (CCH * NCH)            // 256 cols per wave
#define COLS_PER_BLOCK (4 * STRIPE)   // 1024 cols per block
#define NSTEP 60

struct EpsList { float e[NSTEP]; };

struct GramArgs {
  const float* x0; const float* y0;
  const float* x1; const float* y1;
  const float* x2; const float* y2;
  int M0, M1, M2;
  int bs1, bs2, bsTot;
  float* partial;     // [block][800] contiguous fp32
  double* finalG;     // [3][800]
  int atomicMode;
};

// float4 of rows 4rg..4rg+3 (rg 0..3 = x, 4..7 = y) of column c.
__device__ __forceinline__ float* ldsAt(float* buf, int c, int rg) {
  return buf + c * 32 + 4 * (((c >> 2) ^ rg) & 7);
}

__global__ __launch_bounds__(TPB) void gram_kernel(GramArgs A) {
  __shared__ __align__(16) float sE[4][2][1024];   // per-wave double buffer

  const int bid = blockIdx.x;
  int p, lb;
  if (bid >= A.bs2)      { p = 2; lb = bid - A.bs2; }
  else if (bid >= A.bs1) { p = 1; lb = bid - A.bs1; }
  else                   { p = 0; lb = bid; }
  const float* X = (p == 0) ? A.x0 : (p == 1) ? A.x1 : A.x2;
  const float* Y = (p == 0) ? A.y0 : (p == 1) ? A.y1 : A.y2;
  const int M    = (p == 0) ? A.M0 : (p == 1) ? A.M1 : A.M2;

  const int t    = threadIdx.x;
  const int w    = t >> 6;        // wave in block (0..3)
  const int lane = t & 63;
  float* buf0 = sE[w][0];
  float* buf1 = sE[w][1];

  // loader: lane = 8h + cl. h 0..7 -> mat = h>>2, row group rg = h&3;
  // cl 0..7 -> cols 4cl..4cl+3.
  const int h   = lane >> 3;
  const int cl  = lane & 7;
  const int mat = h >> 2;
  const int rg  = h & 3;
  const float* P = mat ? Y : X;

  // FMA mapping: 16 (4x4) tiles x 4 column-slices of 8 cols
  const int s    = lane & 3;
  const int tile = lane >> 2;
  const int ti   = tile >> 2;
  const int tk   = tile & 3;

  const size_t colbase = (size_t)(4 * lb + w) * STRIPE;
  const float* lp = P + (size_t)(4 * rg) * M + colbase + 4 * cl;

  float4 LA[4], LB[4];
  float axy[4][4] = {}, axx[4][4] = {}, ayy[4][4] = {};
  float z[4] = {};

  auto issue = [&](float4 (&L)[4], int chunk) {
    const float* ip = lp + (size_t)chunk * CCH;
    #pragma unroll
    for (int q = 0; q < 4; ++q)
      L[q] = *reinterpret_cast<const float4*>(ip + (size_t)q * M);
  };
  auto stage = [&](const float4 (&L)[4], float* buf) {
    #pragma unroll
    for (int j = 0; j < 4; ++j) {
      const int c = 4 * cl + j;
      const float e0 = __expf(((const float*)&L[0])[j]);
      const float e1 = __expf(((const float*)&L[1])[j]);
      const float e2 = __expf(((const float*)&L[2])[j]);
      const float e3 = __expf(((const float*)&L[3])[j]);
      z[0] += e0; z[1] += e1; z[2] += e2; z[3] += e3;
      *reinterpret_cast<float4*>(ldsAt(buf, c, h)) = make_float4(e0, e1, e2, e3);
    }
  };
  auto fma_phase = [&](const float* buf) {
    #pragma unroll
    for (int it = 0; it < 8; ++it) {
      const int c = 8 * s + it;
      const float4 xi = *reinterpret_cast<const float4*>(ldsAt(const_cast<float*>(buf), c, ti));
      const float4 xk = *reinterpret_cast<const float4*>(ldsAt(const_cast<float*>(buf), c, tk));
      const float4 yi = *reinterpret_cast<const float4*>(ldsAt(const_cast<float*>(buf), c, 4 + ti));
      const float4 yk = *reinterpret_cast<const float4*>(ldsAt(const_cast<float*>(buf), c, 4 + tk));
      const float xiA[4] = {xi.x, xi.y, xi.z, xi.w};
      const float xkA[4] = {xk.x, xk.y, xk.z, xk.w};
      const float yiA[4] = {yi.x, yi.y, yi.z, yi.w};
      const float ykA[4] = {yk.x, yk.y, yk.z, yk.w};
      #pragma unroll
      for (int r = 0; r < 4; ++r) {
        #pragma unroll
        for (int u = 0; u < 4; ++u) {
          axy[r][u] = fmaf(xiA[r], ykA[u], axy[r][u]);
          axx[r][u] = fmaf(xiA[r], xkA[u], axx[r][u]);
          ayy[r][u] = fmaf(yiA[r], ykA[u], ayy[r][u]);
        }
      }
    }
  };

  // prologue: chunks 0,1 in flight; stage 0.
  issue(LA, 0);
  issue(LB, 1);
  stage(LA, buf0);
  // steady state: issue k+2 | stage k+1 | FMA k. Every wait satisfied by
  // distance: vmcnt operand issued 1 chunk ago, FMA buffer written 1
  // chunk ago, stage/FMA touch different buffers within an iteration.
  #pragma unroll 1
  for (int k = 0; k < 6; k += 2) {
    issue(LA, k + 2); stage(LB, buf1); fma_phase(buf0);
    issue(LB, k + 3); stage(LA, buf0); fma_phase(buf1);
  }
  stage(LB, buf1); fma_phase(buf0);   // stage 7, FMA 6
  fma_phase(buf1);                    // FMA 7

  // ---- reduce over the 4 column-slices (lane bits 0..1) ----
  #pragma unroll
  for (int r = 0; r < 4; ++r) {
    #pragma unroll
    for (int u = 0; u < 4; ++u) {
      axy[r][u] += __shfl_xor(axy[r][u], 1); axy[r][u] += __shfl_xor(axy[r][u], 2);
      axx[r][u] += __shfl_xor(axx[r][u], 1); axx[r][u] += __shfl_xor(axx[r][u], 2);
      ayy[r][u] += __shfl_xor(ayy[r][u], 1); ayy[r][u] += __shfl_xor(ayy[r][u], 2);
    }
  }
  // ---- z over the 8 column-group lanes (lane bits 0..2) ----
  #pragma unroll
  for (int d = 1; d <= 4; d <<= 1) {
    #pragma unroll
    for (int q = 0; q < 4; ++q) z[q] += __shfl_xor(z[q], d);
  }

  if (A.atomicMode) {
    double* fin = A.finalG + (size_t)p * 800;
    if (s == 0) {
      #pragma unroll
      for (int r = 0; r < 4; ++r) {
        #pragma unroll
        for (int u = 0; u < 4; ++u) {
          const int ib = (4 * ti + r) * 16 + 4 * tk + u;
          atomicAdd(&fin[ib],       (double)axy[r][u]);
          atomicAdd(&fin[256 + ib], (double)axx[r][u]);
          atomicAdd(&fin[512 + ib], (double)ayy[r][u]);
        }
      }
    }
    if (cl == 0) {
      #pragma unroll
      for (int q = 0; q < 4; ++q)
        atomicAdd(&fin[768 + 16 * mat + 4 * rg + q], (double)z[q]);
    }
    return;
  }

  // ---- each wave dumps its 800 partials into its buf0 ----
  if (s == 0) {
    #pragma unroll
    for (int r = 0; r < 4; ++r) {
      const int ib = (4 * ti + r) * 16 + 4 * tk;
      *reinterpret_cast<float4*>(buf0 + ib)       = make_float4(axy[r][0], axy[r][1], axy[r][2], axy[r][3]);
      *reinterpret_cast<float4*>(buf0 + 256 + ib) = make_float4(axx[r][0], axx[r][1], axx[r][2], axx[r][3]);
      *reinterpret_cast<float4*>(buf0 + 512 + ib) = make_float4(ayy[r][0], ayy[r][1], ayy[r][2], ayy[r][3]);
    }
  }
  if (cl == 0)
    *reinterpret_cast<float4*>(buf0 + 768 + 16 * mat + 4 * rg) = make_float4(z[0], z[1], z[2], z[3]);
  __syncthreads();   // only barrier in the kernel
  if (t < 200) {
    const int o4 = 4 * t;
    const float4 v0 = *reinterpret_cast<const float4*>(&sE[0][0][o4]);
    const float4 v1 = *reinterpret_cast<const float4*>(&sE[1][0][o4]);
    const float4 v2 = *reinterpret_cast<const float4*>(&sE[2][0][o4]);
    const float4 v3 = *reinterpret_cast<const float4*>(&sE[3][0][o4]);
    const float4 o = make_float4((v0.x + v1.x) + (v2.x + v3.x),
                                 (v0.y + v1.y) + (v2.y + v3.y),
                                 (v0.z + v1.z) + (v2.z + v3.z),
                                 (v0.w + v1.w) + (v2.w + v3.w));
    *reinterpret_cast<float4*>(A.partial + (size_t)bid * 800 + o4) = o;
  }
}

// 16 partial-rows per block, coalesced contiguous reads (3200 B rows),
// fp64 register accumulation, one atomicAdd per value.
__global__ __launch_bounds__(256) void reduce_kernel(const float* __restrict__ partial,
                                                     double* __restrict__ finalG,
                                                     int nb0, int nb1, int nb2) {
  const int c0 = (nb0 + 15) >> 4, c1 = (nb1 + 15) >> 4;
  const int b = blockIdx.x;
  int p, r0, pstart, cnt;
  if (b < c0)           { p = 0; r0 = b << 4;             pstart = 0;         cnt = nb0; }
  else if (b < c0 + c1) { p = 1; r0 = (b - c0) << 4;      pstart = nb0;       cnt = nb1; }
  else                  { p = 2; r0 = (b - c0 - c1) << 4; pstart = nb0 + nb1; cnt = nb2; }
  const int rows = min(16, cnt - r0);
  const float* src = partial + (size_t)(pstart + r0) * 800;
  const int tt = threadIdx.x;
  double s0 = 0.0, s1 = 0.0, s2 = 0.0, s3 = 0.0;
  #pragma unroll 1
  for (int r = 0; r < rows; ++r) {
    const float* row = src + (size_t)r * 800;
    s0 += (double)row[tt];
    s1 += (double)row[tt + 256];
    s2 += (double)row[tt + 512];
    if (tt < 32) s3 += (double)row[768 + tt];
  }
  double* fin = finalG + (size_t)p * 800;
  atomicAdd(&fin[tt], s0);
  atomicAdd(&fin[tt + 256], s1);
  atomicAdd(&fin[tt + 512], s2);
  if (tt < 32) atomicAdd(&fin[768 + tt], s3);
}

__device__ __forceinline__ float expm1_poly(float d) {
  float pp = 1.0f / 120.0f;
  pp = fmaf(pp, d, 1.0f / 24.0f);
  pp = fmaf(pp, d, 1.0f / 6.0f);
  pp = fmaf(pp, d, 0.5f);
  return fmaf(d * d, pp, d);
}
__device__ __forceinline__ float log1p_poly(float w) {
  float pp = -1.0f / 6.0f;
  pp = fmaf(pp, w, 1.0f / 5.0f);
  pp = fmaf(pp, w, -1.0f / 4.0f);
  pp = fmaf(pp, w, 1.0f / 3.0f);
  pp = fmaf(pp, w, -0.5f);
  return fmaf(w * w, pp, w);
}

// 6 waves in ONE block: wave 2p = (f,g) chains of pair p ; 2p+1 = (a,b)
// self chains. finalize folded in after __syncthreads.
__global__ __launch_bounds__(384) void sinkhorn_kernel(const double* __restrict__ finalG,
                                                       float* __restrict__ out, EpsList E) {
  const int grp  = threadIdx.x >> 6;
  const int p    = grp >> 1;
  const int half = grp & 1;
  const int lane = threadIdx.x & 63;
  const int pot  = lane >> 5;
  const int i    = (lane >> 1) & 15;
  const int jh   = lane & 1;
  const double* G = finalG + p * 800;

  float Crow[8];
  #pragma unroll
  for (int jj = 0; jj < 8; ++jj) {
    const int j = jh * 8 + jj;
    double Cv;
    if (half == 0) {
      const int r = (pot == 0) ? i : j;
      const int c = (pot == 0) ? j : i;
      const double zr = G[768 + r], zc = G[784 + c];
      const double sr = G[256 + 17 * r] / (zr * zr);
      const double sc = G[512 + 17 * c] / (zc * zc);
      Cv = 0.5 * (sr + sc) - G[16 * r + c] / (zr * zc);
    } else if (pot == 0) {
      const double zi_ = G[768 + i], zj_ = G[768 + j];
      const double si_ = G[256 + 17 * i] / (zi_ * zi_);
      const double sj_ = G[256 + 17 * j] / (zj_ * zj_);
      Cv = 0.5 * (si_ + sj_) - G[256 + 16 * i + j] / (zi_ * zj_);
    } else {
      const double zi_ = G[784 + i], zj_ = G[784 + j];
      const double si_ = G[512 + 17 * i] / (zi_ * zi_);
      const double sj_ = G[512 + 17 * j] / (zj_ * zj_);
      Cv = 0.5 * (si_ + sj_) - G[512 + 16 * i + j] / (zi_ * zj_);
    }
    Crow[jj] = (float)Cv;
  }

  const int srcBase = (half == 0) ? ((pot == 0) ? 32 : 0)
                                  : ((pot == 0) ? 0 : 32);
  float h = 0.0f;

  #pragma unroll 1
  for (int n = 0; n < NSTEP; ++n) {
    const float eps  = E.e[n];
    const float inve = 1.0f / eps;
    float q = 0.0f;
    #pragma unroll
    for (int jj = 0; jj < 8; ++jj) {
      const float hj = __shfl(h, srcBase + 2 * (jh * 8 + jj));
      q += expm1_poly((hj - Crow[jj]) * inve);
    }
    q += __shfl_xor(q, 1);
    const float val = -eps * log1p_poly(q * (1.0f / 16.0f));
    h = 0.5f * (h + val);
  }
  {
    const float eps  = 0.0025f;
    const float inve = 1.0f / eps;
    float q = 0.0f;
    #pragma unroll
    for (int jj = 0; jj < 8; ++jj) {
      const float hj = __shfl(h, srcBase + 2 * (jh * 8 + jj));
      q += expm1_poly((hj - Crow[jj]) * inve);
    }
    q += __shfl_xor(q, 1);
    h = -eps * log1p_poly(q * (1.0f / 16.0f));
  }
  float sAcc = h;
  #pragma unroll
  for (int d = 1; d <= 32; d <<= 1) sAcc += __shfl_xor(sAcc, d);

  __shared__ double res[6];
  if (lane == 0) res[grp] = (double)(sAcc * (1.0f / 32.0f));
  __syncthreads();
  if (threadIdx.x == 0) {
    const double v = (res[0] - res[1]) + (res[2] - res[3]) + (res[4] - res[5]);
    out[0] = (float)(v / 3.0);
  }
}

extern "C" void kernel_launch(void* const* d_in, const int* in_sizes, int n_in,
                              void* d_out, int out_size, void* d_ws, size_t ws_size,
                              hipStream_t stream) {
  (void)n_in; (void)out_size;
  int idx[6] = {0, 1, 2, 3, 4, 5};
  for (int a = 1; a < 6; ++a) {
    const int key = idx[a];
    int b = a - 1;
    while (b >= 0 && in_sizes[idx[b]] < in_sizes[key]) { idx[b + 1] = idx[b]; --b; }
    idx[b + 1] = key;
  }

  const float* xs[3]; const float* ys[3]; int Ms[3]; int nb[3];
  for (int p = 0; p < 3; ++p) {
    xs[p] = (const float*)d_in[idx[2 * p]];
    ys[p] = (const float*)d_in[idx[2 * p + 1]];
    Ms[p] = in_sizes[idx[2 * p]] / 16;
    nb[p] = Ms[p] / COLS_PER_BLOCK;
  }
  const int totalBlocks = nb[0] + nb[1] + nb[2];

  const size_t partialBytes = (size_t)totalBlocks * 800 * sizeof(float);
  const size_t finalBytes   = (size_t)2400 * sizeof(double);
  const bool partialMode    = (ws_size >= partialBytes + finalBytes);

  char* wsb      = (char*)d_ws;
  float* partial = partialMode ? (float*)wsb : nullptr;
  double* finalG = (double*)(wsb + (partialMode ? partialBytes : 0));

  hipMemsetAsync(finalG, 0, finalBytes, stream);

  GramArgs A;
  A.x0 = xs[0]; A.y0 = ys[0];
  A.x1 = xs[1]; A.y1 = ys[1];
  A.x2 = xs[2]; A.y2 = ys[2];
  A.M0 = Ms[0]; A.M1 = Ms[1]; A.M2 = Ms[2];
  A.bs1 = nb[0]; A.bs2 = nb[0] + nb[1]; A.bsTot = totalBlocks;
  A.partial = partial; A.finalG = finalG;
  A.atomicMode = partialMode ? 0 : 1;

  gram_kernel<<<dim3(totalBlocks), dim3(TPB), 0, stream>>>(A);
  if (partialMode) {
    const int rb = ((nb[0] + 15) / 16) + ((nb[1] + 15) / 16) + ((nb[2] + 15) / 16);
    reduce_kernel<<<dim3(rb), dim3(256), 0, stream>>>(partial, finalG, nb[0], nb[1], nb[2]);
  }

  EpsList E;
  const double base = 0.95 * 0.95;
  for (int n = 0; n < NSTEP; ++n) {
    double v = pow(base, (double)n);
    if (v < 0.0025) v = 0.0025;
    E.e[n] = (float)v;
  }
  sinkhorn_kernel<<<dim3(1), dim3(384), 0, stream>>>(finalG, (float*)d_out, E);
}

// Round 4
// 263.945 us; speedup vs baseline: 1.0267x; 1.0267x over previous
//
#include <hip/hip_runtime.h>
#include <cmath>

// R8: MFMA gram, zero LDS in main loop. R4-R7: four structurally different
// VALU+LDS-transpose pipelines all pinned at ~100us / VALUBusy 27%, and
// L3-warm iterations (5.7MB fetch) ran the SAME speed as 114MB-fetch ones
// -> the fp32 VALU+LDS structure itself was the floor, not memory/latency.
// Pivot: for a 16-row Gram, MFMA A-frag and B-frag share one lane layout
// (lane&15=row, lane>>4 -> 8 contiguous k) == our row-major [16][M] data.
// Each lane loads its fragment directly from global: NO transpose, NO LDS,
// 36 DS ops/chunk -> 0, ~530 VALU/chunk -> ~180.
//  - fp32 via bf16 hi/lo split (RNE): G = hi*hi + hi*lo + lo*hi per gram
//    (drop lo*lo ~ 2^-16 rel). All-positive sums -> G rel err ~1e-6.
//  - z row-sums via MFMA vs ones-fragment: every consumed value (G, z)
//    then shares the fragment's row map -> result invariant to any
//    row/k permutation of the A/B layout. C-store uses the HW-verified
//    map col=lane&15, row=(lane>>4)*4+reg.
//  - 13 MFMA + 4 global dwordx4 + ~180 VALU per K=32 chunk per wave.
//  - partial [block][800] / reduce / fused sinkhorn+finalize unchanged.

#define TPB 256
#define WCOLS 256                     // columns per wave = 8 chunks of K=32
#define COLS_PER_BLOCK (4 * WCOLS)    // 1024
#define NSTEP 60

typedef short short8 __attribute__((ext_vector_type(8)));   // 8 x bf16 frag
typedef float f32x4 __attribute__((ext_vector_type(4)));    // MFMA acc

struct EpsList { float e[NSTEP]; };

struct GramArgs {
  const float* x0; const float* y0;
  const float* x1; const float* y1;
  const float* x2; const float* y2;
  int M0, M1, M2;
  int bs1, bs2, bsTot;
  float* partial;     // [block][800] contiguous fp32
  double* finalG;     // [3][800]
  int atomicMode;
};

__device__ __forceinline__ short f2bf_rne(float f) {
  unsigned u = __float_as_uint(f);
  u += 0x7FFFu + ((u >> 16) & 1u);
  return (short)(u >> 16);
}
__device__ __forceinline__ float bf2f(short h) {
  return __uint_as_float(((unsigned)(unsigned short)h) << 16);
}

#define SPLIT(HI, LO, J, VAL)                                   \
  { const float fv_ = (VAL); const short hh_ = f2bf_rne(fv_);   \
    HI[J] = hh_; LO[J] = f2bf_rne(fv_ - bf2f(hh_)); }

__global__ __launch_bounds__(TPB) void gram_kernel(GramArgs A) {
  __shared__ __align__(16) float sB[4][800];

  const int bid = blockIdx.x;
  int p, lb;
  if (bid >= A.bs2)      { p = 2; lb = bid - A.bs2; }
  else if (bid >= A.bs1) { p = 1; lb = bid - A.bs1; }
  else                   { p = 0; lb = bid; }
  const float* X = (p == 0) ? A.x0 : (p == 1) ? A.x1 : A.x2;
  const float* Y = (p == 0) ? A.y0 : (p == 1) ? A.y1 : A.y2;
  const int M    = (p == 0) ? A.M0 : (p == 1) ? A.M1 : A.M2;

  const int t    = threadIdx.x;
  const int w    = t >> 6;
  const int lane = t & 63;
  const int r    = lane & 15;    // fragment row
  const int kg   = lane >> 4;    // k-group (8 contiguous k)

  const size_t wbase = (size_t)(4 * lb + w) * WCOLS;
  const float* qx = X + (size_t)r * M + wbase + 8 * kg;
  const float* qy = Y + (size_t)r * M + wbase + 8 * kg;

  f32x4 aXY = {0.f, 0.f, 0.f, 0.f};
  f32x4 aXX = {0.f, 0.f, 0.f, 0.f};
  f32x4 aYY = {0.f, 0.f, 0.f, 0.f};
  f32x4 aZX = {0.f, 0.f, 0.f, 0.f};
  f32x4 aZY = {0.f, 0.f, 0.f, 0.f};
  short8 ones;
  #pragma unroll
  for (int j = 0; j < 8; ++j) ones[j] = (short)0x3F80;   // bf16 1.0

  #pragma unroll 1
  for (int c = 0; c < 8; ++c) {
    const float4 x0 = *reinterpret_cast<const float4*>(qx);
    const float4 x1 = *reinterpret_cast<const float4*>(qx + 4);
    const float4 y0 = *reinterpret_cast<const float4*>(qy);
    const float4 y1 = *reinterpret_cast<const float4*>(qy + 4);
    qx += 32; qy += 32;

    short8 hx, lx, hy, ly;
    SPLIT(hx, lx, 0, __expf(x0.x)); SPLIT(hx, lx, 1, __expf(x0.y));
    SPLIT(hx, lx, 2, __expf(x0.z)); SPLIT(hx, lx, 3, __expf(x0.w));
    SPLIT(hx, lx, 4, __expf(x1.x)); SPLIT(hx, lx, 5, __expf(x1.y));
    SPLIT(hx, lx, 6, __expf(x1.z)); SPLIT(hx, lx, 7, __expf(x1.w));
    SPLIT(hy, ly, 0, __expf(y0.x)); SPLIT(hy, ly, 1, __expf(y0.y));
    SPLIT(hy, ly, 2, __expf(y0.z)); SPLIT(hy, ly, 3, __expf(y0.w));
    SPLIT(hy, ly, 4, __expf(y1.x)); SPLIT(hy, ly, 5, __expf(y1.y));
    SPLIT(hy, ly, 6, __expf(y1.z)); SPLIT(hy, ly, 7, __expf(y1.w));

    // round-robin over the 5 accumulators -> dep distance >= 5
    aXY = __builtin_amdgcn_mfma_f32_16x16x32_bf16(hx, hy, aXY, 0, 0, 0);
    aXX = __builtin_amdgcn_mfma_f32_16x16x32_bf16(hx, hx, aXX, 0, 0, 0);
    aYY = __builtin_amdgcn_mfma_f32_16x16x32_bf16(hy, hy, aYY, 0, 0, 0);
    aZX = __builtin_amdgcn_mfma_f32_16x16x32_bf16(hx, ones, aZX, 0, 0, 0);
    aZY = __builtin_amdgcn_mfma_f32_16x16x32_bf16(hy, ones, aZY, 0, 0, 0);
    aXY = __builtin_amdgcn_mfma_f32_16x16x32_bf16(hx, ly, aXY, 0, 0, 0);
    aXX = __builtin_amdgcn_mfma_f32_16x16x32_bf16(hx, lx, aXX, 0, 0, 0);
    aYY = __builtin_amdgcn_mfma_f32_16x16x32_bf16(hy, ly, aYY, 0, 0, 0);
    aZX = __builtin_amdgcn_mfma_f32_16x16x32_bf16(lx, ones, aZX, 0, 0, 0);
    aZY = __builtin_amdgcn_mfma_f32_16x16x32_bf16(ly, ones, aZY, 0, 0, 0);
    aXY = __builtin_amdgcn_mfma_f32_16x16x32_bf16(lx, hy, aXY, 0, 0, 0);
    aXX = __builtin_amdgcn_mfma_f32_16x16x32_bf16(lx, hx, aXX, 0, 0, 0);
    aYY = __builtin_amdgcn_mfma_f32_16x16x32_bf16(ly, hy, aYY, 0, 0, 0);
  }

  // C layout (HW-verified m89): col = lane&15, row = (lane>>4)*4 + reg.
  if (A.atomicMode) {
    double* fin = A.finalG + (size_t)p * 800;
    #pragma unroll
    for (int j = 0; j < 4; ++j) {
      const int ib = (4 * kg + j) * 16 + r;
      atomicAdd(&fin[ib],       (double)aXY[j]);
      atomicAdd(&fin[256 + ib], (double)aXX[j]);
      atomicAdd(&fin[512 + ib], (double)aYY[j]);
    }
    if (r == 0) {
      #pragma unroll
      for (int j = 0; j < 4; ++j) {
        atomicAdd(&fin[768 + 4 * kg + j], (double)aZX[j]);
        atomicAdd(&fin[784 + 4 * kg + j], (double)aZY[j]);
      }
    }
    return;
  }

  float* b = sB[w];
  #pragma unroll
  for (int j = 0; j < 4; ++j) {
    const int ib = (4 * kg + j) * 16 + r;
    b[ib]       = aXY[j];
    b[256 + ib] = aXX[j];
    b[512 + ib] = aYY[j];
  }
  if (r == 0) {
    #pragma unroll
    for (int j = 0; j < 4; ++j) {
      b[768 + 4 * kg + j] = aZX[j];   // zx[row], any column holds it
      b[784 + 4 * kg + j] = aZY[j];
    }
  }
  __syncthreads();
  if (t < 200) {
    const int o4 = 4 * t;
    const float4 v0 = *reinterpret_cast<const float4*>(&sB[0][o4]);
    const float4 v1 = *reinterpret_cast<const float4*>(&sB[1][o4]);
    const float4 v2 = *reinterpret_cast<const float4*>(&sB[2][o4]);
    const float4 v3 = *reinterpret_cast<const float4*>(&sB[3][o4]);
    const float4 o = make_float4((v0.x + v1.x) + (v2.x + v3.x),
                                 (v0.y + v1.y) + (v2.y + v3.y),
                                 (v0.z + v1.z) + (v2.z + v3.z),
                                 (v0.w + v1.w) + (v2.w + v3.w));
    *reinterpret_cast<float4*>(A.partial + (size_t)bid * 800 + o4) = o;
  }
}

// 16 partial-rows per block, coalesced contiguous reads (3200 B rows),
// fp64 register accumulation, one atomicAdd per value.
__global__ __launch_bounds__(256) void reduce_kernel(const float* __restrict__ partial,
                                                     double* __restrict__ finalG,
                                                     int nb0, int nb1, int nb2) {
  const int c0 = (nb0 + 15) >> 4, c1 = (nb1 + 15) >> 4;
  const int b = blockIdx.x;
  int p, r0, pstart, cnt;
  if (b < c0)           { p = 0; r0 = b << 4;             pstart = 0;         cnt = nb0; }
  else if (b < c0 + c1) { p = 1; r0 = (b - c0) << 4;      pstart = nb0;       cnt = nb1; }
  else                  { p = 2; r0 = (b - c0 - c1) << 4; pstart = nb0 + nb1; cnt = nb2; }
  const int rows = min(16, cnt - r0);
  const float* src = partial + (size_t)(pstart + r0) * 800;
  const int tt = threadIdx.x;
  double s0 = 0.0, s1 = 0.0, s2 = 0.0, s3 = 0.0;
  #pragma unroll 1
  for (int rr = 0; rr < rows; ++rr) {
    const float* row = src + (size_t)rr * 800;
    s0 += (double)row[tt];
    s1 += (double)row[tt + 256];
    s2 += (double)row[tt + 512];
    if (tt < 32) s3 += (double)row[768 + tt];
  }
  double* fin = finalG + (size_t)p * 800;
  atomicAdd(&fin[tt], s0);
  atomicAdd(&fin[tt + 256], s1);
  atomicAdd(&fin[tt + 512], s2);
  if (tt < 32) atomicAdd(&fin[768 + tt], s3);
}

__device__ __forceinline__ float expm1_poly(float d) {
  float pp = 1.0f / 120.0f;
  pp = fmaf(pp, d, 1.0f / 24.0f);
  pp = fmaf(pp, d, 1.0f / 6.0f);
  pp = fmaf(pp, d, 0.5f);
  return fmaf(d * d, pp, d);
}
__device__ __forceinline__ float log1p_poly(float w) {
  float pp = -1.0f / 6.0f;
  pp = fmaf(pp, w, 1.0f / 5.0f);
  pp = fmaf(pp, w, -1.0f / 4.0f);
  pp = fmaf(pp, w, 1.0f / 3.0f);
  pp = fmaf(pp, w, -0.5f);
  return fmaf(w * w, pp, w);
}

// 6 waves in ONE block: wave 2p = (f,g) chains of pair p ; 2p+1 = (a,b)
// self chains. finalize folded in after __syncthreads.
__global__ __launch_bounds__(384) void sinkhorn_kernel(const double* __restrict__ finalG,
                                                       float* __restrict__ out, EpsList E) {
  const int grp  = threadIdx.x >> 6;
  const int p    = grp >> 1;
  const int half = grp & 1;
  const int lane = threadIdx.x & 63;
  const int pot  = lane >> 5;
  const int i    = (lane >> 1) & 15;
  const int jh   = lane & 1;
  const double* G = finalG + p * 800;

  float Crow[8];
  #pragma unroll
  for (int jj = 0; jj < 8; ++jj) {
    const int j = jh * 8 + jj;
    double Cv;
    if (half == 0) {
      const int rr = (pot == 0) ? i : j;
      const int cc = (pot == 0) ? j : i;
      const double zr = G[768 + rr], zc = G[784 + cc];
      const double sr = G[256 + 17 * rr] / (zr * zr);
      const double sc = G[512 + 17 * cc] / (zc * zc);
      Cv = 0.5 * (sr + sc) - G[16 * rr + cc] / (zr * zc);
    } else if (pot == 0) {
      const double zi_ = G[768 + i], zj_ = G[768 + j];
      const double si_ = G[256 + 17 * i] / (zi_ * zi_);
      const double sj_ = G[256 + 17 * j] / (zj_ * zj_);
      Cv = 0.5 * (si_ + sj_) - G[256 + 16 * i + j] / (zi_ * zj_);
    } else {
      const double zi_ = G[784 + i], zj_ = G[784 + j];
      const double si_ = G[512 + 17 * i] / (zi_ * zi_);
      const double sj_ = G[512 + 17 * j] / (zj_ * zj_);
      Cv = 0.5 * (si_ + sj_) - G[512 + 16 * i + j] / (zi_ * zj_);
    }
    Crow[jj] = (float)Cv;
  }

  const int srcBase = (half == 0) ? ((pot == 0) ? 32 : 0)
                                  : ((pot == 0) ? 0 : 32);
  float h = 0.0f;

  #pragma unroll 1
  for (int n = 0; n < NSTEP; ++n) {
    const float eps  = E.e[n];
    const float inve = 1.0f / eps;
    float q = 0.0f;
    #pragma unroll
    for (int jj = 0; jj < 8; ++jj) {
      const float hj = __shfl(h, srcBase + 2 * (jh * 8 + jj));
      q += expm1_poly((hj - Crow[jj]) * inve);
    }
    q += __shfl_xor(q, 1);
    const float val = -eps * log1p_poly(q * (1.0f / 16.0f));
    h = 0.5f * (h + val);
  }
  {
    const float eps  = 0.0025f;
    const float inve = 1.0f / eps;
    float q = 0.0f;
    #pragma unroll
    for (int jj = 0; jj < 8; ++jj) {
      const float hj = __shfl(h, srcBase + 2 * (jh * 8 + jj));
      q += expm1_poly((hj - Crow[jj]) * inve);
    }
    q += __shfl_xor(q, 1);
    h = -eps * log1p_poly(q * (1.0f / 16.0f));
  }
  float sAcc = h;
  #pragma unroll
  for (int d = 1; d <= 32; d <<= 1) sAcc += __shfl_xor(sAcc, d);

  __shared__ double res[6];
  if (lane == 0) res[grp] = (double)(sAcc * (1.0f / 32.0f));
  __syncthreads();
  if (threadIdx.x == 0) {
    const double v = (res[0] - res[1]) + (res[2] - res[3]) + (res[4] - res[5]);
    out[0] = (float)(v / 3.0);
  }
}

extern "C" void kernel_launch(void* const* d_in, const int* in_sizes, int n_in,
                              void* d_out, int out_size, void* d_ws, size_t ws_size,
                              hipStream_t stream) {
  (void)n_in; (void)out_size;
  int idx[6] = {0, 1, 2, 3, 4, 5};
  for (int a = 1; a < 6; ++a) {
    const int key = idx[a];
    int b = a - 1;
    while (b >= 0 && in_sizes[idx[b]] < in_sizes[key]) { idx[b + 1] = idx[b]; --b; }
    idx[b + 1] = key;
  }

  const float* xs[3]; const float* ys[3]; int Ms[3]; int nb[3];
  for (int p = 0; p < 3; ++p) {
    xs[p] = (const float*)d_in[idx[2 * p]];
    ys[p] = (const float*)d_in[idx[2 * p + 1]];
    Ms[p] = in_sizes[idx[2 * p]] / 16;
    nb[p] = Ms[p] / COLS_PER_BLOCK;
  }
  const int totalBlocks = nb[0] + nb[1] + nb[2];

  const size_t partialBytes = (size_t)totalBlocks * 800 * sizeof(float);
  const size_t finalBytes   = (size_t)2400 * sizeof(double);
  const bool partialMode    = (ws_size >= partialBytes + finalBytes);

  char* wsb      = (char*)d_ws;
  float* partial = partialMode ? (float*)wsb : nullptr;
  double* finalG = (double*)(wsb + (partialMode ? partialBytes : 0));

  hipMemsetAsync(finalG, 0, finalBytes, stream);

  GramArgs A;
  A.x0 = xs[0]; A.y0 = ys[0];
  A.x1 = xs[1]; A.y1 = ys[1];
  A.x2 = xs[2]; A.y2 = ys[2];
  A.M0 = Ms[0]; A.M1 = Ms[1]; A.M2 = Ms[2];
  A.bs1 = nb[0]; A.bs2 = nb[0] + nb[1]; A.bsTot = totalBlocks;
  A.partial = partial; A.finalG = finalG;
  A.atomicMode = partialMode ? 0 : 1;

  gram_kernel<<<dim3(totalBlocks), dim3(TPB), 0, stream>>>(A);
  if (partialMode) {
    const int rb = ((nb[0] + 15) / 16) + ((nb[1] + 15) / 16) + ((nb[2] + 15) / 16);
    reduce_kernel<<<dim3(rb), dim3(256), 0, stream>>>(partial, finalG, nb[0], nb[1], nb[2]);
  }

  EpsList E;
  const double base = 0.95 * 0.95;
  for (int n = 0; n < NSTEP; ++n) {
    double v = pow(base, (double)n);
    if (v < 0.0025) v = 0.0025;
    E.e[n] = (float)v;
  }
  sinkhorn_kernel<<<dim3(1), dim3(384), 0, stream>>>(finalG, (float*)d_out, E);
}